// Round 14
// baseline (232.980 us; speedup 1.0000x reference)
//
#include <hip/hip_runtime.h>

typedef unsigned short u16;
typedef unsigned int u32;
typedef __bf16 v8bf __attribute__((ext_vector_type(8)));
typedef float v4f __attribute__((ext_vector_type(4)));

#define DEV __device__ __forceinline__

constexpr int CB = 4;     // batch
constexpr int C = 256;    // channels
constexpr int NN = 4096;  // voxels
constexpr float LOG2E = 1.4426950408889634f;
constexpr int PST = 44;   // P LDS row stride (u16): 88B = 22 banks -> conflict-free writes

DEV u16 f2bf(float f) {
  union { float f; u32 u; } v; v.f = f;
  u32 r = v.u + 0x7fffu + ((v.u >> 16) & 1u);  // RNE
  return (u16)(r >> 16);
}
DEV float bf2f(u16 h) {
  union { u32 u; float f; } v; v.u = ((u32)h) << 16; return v.f;
}

// async global->LDS DMA, 16B per lane; LDS dest = wave-uniform base + lane*16
DEV void dma16(const u16* g, const u16* lds_base) {
  __builtin_amdgcn_global_load_lds(
      (const __attribute__((address_space(1))) void*)(unsigned long long)g,
      (__attribute__((address_space(3))) void*)(u32)(unsigned long long)lds_base,
      16, 0, 0);
}

// ---------- weight fp32->bf16 convert + Mbuf zero ----------
__global__ __launch_bounds__(256) void k_prep(const float* __restrict__ s0,
                                              const float* __restrict__ s1,
                                              const float* __restrict__ s2,
                                              const float* __restrict__ s3,
                                              u16* __restrict__ d0, u16* __restrict__ d1,
                                              u16* __restrict__ d2, u16* __restrict__ d3,
                                              float* __restrict__ Mbuf) {
  if (blockIdx.x == 0 && blockIdx.y == 0 && threadIdx.x < 8) Mbuf[threadIdx.x] = 0.f;
  int wsel = blockIdx.y;
  const float* s = wsel == 0 ? s0 : wsel == 1 ? s1 : wsel == 2 ? s2 : s3;
  u16* d = wsel == 0 ? d0 : wsel == 1 ? d1 : wsel == 2 ? d2 : d3;
  int i = blockIdx.x * 256 + threadIdx.x;
  d[i] = f2bf(s[i]);
}

// ---------- stage 64 rows x 256 u16 into linear LDS [64][256] via DMA ----------
// Column-group (8 u16) XOR-swizzle: LDS slot s holds global group s ^ (row&7).
// Read side applies the same XOR (T21: linear dest + pre-swizzled source).
DEV void stage_dma(const u16* __restrict__ g, const u16* lds, int w, int lane) {
#pragma unroll
  for (int i = 0; i < 8; ++i) {
    int idx = w * 8 + i;
    int r = idx * 2 + (lane >> 5);
    int cg = (lane & 31) ^ (r & 7);
    dma16(g + (long)r * 256 + cg * 8, lds + idx * 512);
  }
}

// ---------- fused transpose + q/k/v projection + row-norm^2 partials ----------
// A-tile built DIRECTLY from x (fp32, (B,C,N) layout): block reads its
// 64-voxel x 256-ch tile (64KB; the 4 quarter-blocks of the same m0 share it
// via L2), transposes in-LDS (Bsh as fp32 scratch), writes the SAME
// XOR-swizzled bf16 layout stage_dma produced. Kills the xT intermediate
// (33.5MB write + 33.5MB read) and the separate transpose kernel.
// A-build pattern is the round-8-verified code (it passed the harness).
// Pn[tsel][quarter][b][gm]: per-64-ch-quarter sumsq of scaled q'/k rows.
__global__ __launch_bounds__(256) void k_qkv(
    const float* __restrict__ x, const u16* __restrict__ wqb,
    const u16* __restrict__ wkb, const u16* __restrict__ wvb,
    const float* __restrict__ bq, const float* __restrict__ bk,
    const float* __restrict__ bv, u16* __restrict__ qO, u16* __restrict__ kO,
    u16* __restrict__ vO, float* __restrict__ Pn) {
  __shared__ __align__(16) u16 Ash[64 * 256];
  __shared__ __align__(16) u16 Bsh[64 * 256];
  int t = threadIdx.x, w = t >> 6, lane = t & 63, lr = lane & 15, q = lane >> 4;
  int m0 = blockIdx.x * 64, n0 = blockIdx.y * 64, b = blockIdx.z;
  const int xk = lr & 7;

  // ---- build A: x[b][c][m0..m0+63] -> Ash[n][(group)^(n&7)] bf16, 4 c-chunks
  {
    float* scr = (float*)Bsh;  // [64][65] fp32 scratch (16.6 KB)
#pragma unroll 1
    for (int cc = 0; cc < 4; ++cc) {
#pragma unroll
      for (int p = 0; p < 4; ++p) {
        int cl = p * 16 + (t >> 4);        // 0..63 (c within chunk)
        int nl = (t & 15) * 4;             // 0..60
        *reinterpret_cast<float4*>(&scr[cl * 65 + nl]) =
            *reinterpret_cast<const float4*>(
                &x[((long)b * C + cc * 64 + cl) * NN + m0 + nl]);
      }
      __syncthreads();
      int n = t >> 2;                      // 0..63 (voxel row)
      int c0l = (t & 3) * 16;              // c base within chunk
#pragma unroll
      for (int j = 0; j < 2; ++j) {
        u16 tmp[8];
#pragma unroll
        for (int e = 0; e < 8; ++e) tmp[e] = f2bf(scr[(c0l + j * 8 + e) * 65 + n]);
        int cg = (cc * 8 + (t & 3) * 2 + j) ^ (n & 7);
        *reinterpret_cast<uint4*>(&Ash[n * 256 + cg * 8]) =
            *reinterpret_cast<const uint4*>(tmp);
      }
      __syncthreads();
    }
  }

  stage_dma(wqb + (long)n0 * 256, Bsh, w, lane);
  asm volatile("s_waitcnt vmcnt(0)\n\ts_barrier" ::: "memory");
#pragma unroll 1
  for (int wsel = 0; wsel < 3; ++wsel) {
    v4f acc[4];
#pragma unroll
    for (int nt = 0; nt < 4; ++nt)
#pragma unroll
      for (int r = 0; r < 4; ++r) acc[nt][r] = 0.f;
#pragma unroll
    for (int ks = 0; ks < 8; ++ks) {
      int cg = ((ks * 4 + q) ^ xk) << 3;
      v8bf a = *reinterpret_cast<const v8bf*>(Ash + (w * 16 + lr) * 256 + cg);
#pragma unroll
      for (int nt = 0; nt < 4; ++nt) {
        v8bf bb = *reinterpret_cast<const v8bf*>(Bsh + (nt * 16 + lr) * 256 + cg);
        acc[nt] = __builtin_amdgcn_mfma_f32_16x16x32_bf16(a, bb, acc[nt], 0, 0, 0);
      }
    }
    // all waves done reading Ash/Bsh before we overwrite either
    asm volatile("s_waitcnt lgkmcnt(0)\n\ts_barrier" ::: "memory");
    if (wsel < 2) {
      stage_dma((wsel == 0 ? wkb : wvb) + (long)n0 * 256, Bsh, w, lane);
      // epilogue overlaps the B-restage DMA flight
      const float* bias = wsel == 0 ? bq : bk;
      float sn[4] = {0.f, 0.f, 0.f, 0.f};
#pragma unroll
      for (int nt = 0; nt < 4; ++nt) {
#pragma unroll
        for (int r = 0; r < 4; ++r) {
          int gm = m0 + w * 16 + q * 4 + r;   // voxel
          int gn = n0 + nt * 16 + lr;         // out channel
          float val = acc[nt][r] + bias[gn];
          if (wsel == 0) {
            float vs = val * (0.0625f * LOG2E);
            qO[((long)b * NN + gm) * C + gn] = f2bf(vs);
            sn[r] += vs * vs;
          } else {
            kO[((long)b * NN + gm) * C + gn] = f2bf(val);
            sn[r] += val * val;
          }
        }
      }
#pragma unroll
      for (int r = 0; r < 4; ++r) {
#pragma unroll
        for (int d = 1; d < 16; d <<= 1) sn[r] += __shfl_xor(sn[r], d, 64);
      }
      if (lr == 0) {
#pragma unroll
        for (int r = 0; r < 4; ++r)
          Pn[(((long)wsel * 4 + blockIdx.y) * CB + b) * NN + m0 + w * 16 + q * 4 + r] =
              sn[r];
      }
      asm volatile("s_waitcnt vmcnt(0)\n\ts_barrier" ::: "memory");
    } else {
      // V output: bounce through Ash (dead now) so the (C,N)-layout store
      // is coalesced uint4 instead of a 64-lane 2B scatter at 8KB stride.
      u16* Vt = Ash;  // 64 ch rows x stride 72 u16 (144B, debanked)
#pragma unroll
      for (int nt = 0; nt < 4; ++nt) {
#pragma unroll
        for (int r = 0; r < 4; ++r) {
          int gn_l = nt * 16 + lr;            // local out channel
          int gm_l = w * 16 + q * 4 + r;      // local voxel
          float val = acc[nt][r] + bv[n0 + gn_l];
          Vt[gn_l * 72 + gm_l] = f2bf(val);
        }
      }
      asm volatile("s_waitcnt lgkmcnt(0)\n\ts_barrier" ::: "memory");
      int row = t >> 2;                        // 0..63 local channel
      u16* vrow = vO + (long)b * C * NN + (long)(n0 + row) * NN + m0;
#pragma unroll
      for (int s2 = 0; s2 < 2; ++s2) {
        int seg = (t & 3) * 2 + s2;            // 0..7 (8 u16 each)
        *reinterpret_cast<uint4*>(vrow + seg * 8) =
            *reinterpret_cast<const uint4*>(Vt + row * 72 + seg * 8);
      }
    }
  }
}

// ---------- reduce the 4 ch-quarter partials -> per-batch max row-norm^2 ------
__global__ __launch_bounds__(256) void k_norm(const float* __restrict__ Pn,
                                              float* __restrict__ Mbuf) {
  int tsel = blockIdx.y, b = blockIdx.z;
  float mx = 0.f;
  for (int row = threadIdx.x; row < NN; row += 256) {
    float s = 0.f;
#pragma unroll
    for (int qr = 0; qr < 4; ++qr)
      s += Pn[(((long)tsel * 4 + qr) * CB + b) * NN + row];
    mx = fmaxf(mx, s);
  }
#pragma unroll
  for (int d = 1; d < 64; d <<= 1) mx = fmaxf(mx, __shfl_xor(mx, d, 64));
  if ((threadIdx.x & 63) == 0)
    atomicMax((u32*)(Mbuf + tsel * 4 + b), __float_as_uint(mx));
}

// issue the 4 K-DMAs for one 32-j tile (this wave's quarter), XOR-swizzled
DEV void kissue(const u16* kb, const u16* kshb, int j0, int w, int lane) {
#pragma unroll
  for (int i = 0; i < 4; ++i) {
    int idx = w * 4 + i;
    int kr = idx * 2 + (lane >> 5);
    int kc = (lane & 31) ^ (kr & 7);
    dma16(kb + (long)(j0 + kr) * 256 + kc * 8, kshb + idx * 512);
  }
}

// ---------- flash attention: single barrier per j-tile, software-pipelined ----
// qT,kT: (B,N,C) bf16 (q pre-scaled by C^-0.5*log2e); V: (B,C,N) bf16
// (frozen round-7 structure: 4 indep QK MFMA chains, setprio, XCD swizzle)
#define FLASH_STEP(IT, VL, VU, PW, PR, KC, KN)                                     \
  {                                                                                \
    int jn_ = ((IT) + 1 < niter) ? jstart + (((IT) + 1) << 5) : jstart;            \
    kissue(kb, (KN), jn_, w, lane);                                                \
    asm volatile("" ::: "memory"); /* keep K-DMAs older than V loads in vmcnt */   \
    {                                                                              \
      int jv_ = jstart + ((IT) << 5);                                              \
      _Pragma("unroll") for (int cs = 0; cs < 4; ++cs)                             \
          VL[cs] = *reinterpret_cast<const v8bf*>(                                 \
              vbw + (long)(cs * 16 + lr) * NN + jv_ + q * 8);                      \
    }                                                                              \
    v4f s0a_, s0b_, s1a_, s1b_;                                                    \
    _Pragma("unroll") for (int r = 0; r < 4; ++r) {                                \
      s0a_[r] = 0.f; s0b_[r] = 0.f; s1a_[r] = 0.f; s1b_[r] = 0.f;                  \
    }                                                                              \
    __builtin_amdgcn_s_setprio(1);                                                 \
    _Pragma("unroll") for (int ks = 0; ks < 4; ++ks) {                             \
      int cgA_ = ((ks * 4 + q) ^ xk) << 3;                                         \
      int cgB_ = (((ks + 4) * 4 + q) ^ xk) << 3;                                   \
      v8bf k0a_ = *reinterpret_cast<const v8bf*>((KC) + lr * 256 + cgA_);          \
      v8bf k1a_ = *reinterpret_cast<const v8bf*>((KC) + (16 + lr) * 256 + cgA_);   \
      v8bf k0b_ = *reinterpret_cast<const v8bf*>((KC) + lr * 256 + cgB_);          \
      v8bf k1b_ = *reinterpret_cast<const v8bf*>((KC) + (16 + lr) * 256 + cgB_);   \
      s0a_ = __builtin_amdgcn_mfma_f32_16x16x32_bf16(qf[ks], k0a_, s0a_, 0, 0, 0); \
      s1a_ = __builtin_amdgcn_mfma_f32_16x16x32_bf16(qf[ks], k1a_, s1a_, 0, 0, 0); \
      s0b_ = __builtin_amdgcn_mfma_f32_16x16x32_bf16(qf[ks + 4], k0b_, s0b_, 0, 0, 0); \
      s1b_ = __builtin_amdgcn_mfma_f32_16x16x32_bf16(qf[ks + 4], k1b_, s1b_, 0, 0, 0); \
    }                                                                              \
    __builtin_amdgcn_s_setprio(0);                                                 \
    v4f s0_ = s0a_ + s0b_;                                                         \
    v4f s1_ = s1a_ + s1b_;                                                         \
    _Pragma("unroll") for (int r = 0; r < 4; ++r) {                                \
      float p0_ = exp2f(s0_[r] - M);                                               \
      float p1_ = exp2f(s1_[r] - M);                                               \
      lsum[r] += p0_ + p1_;                                                        \
      (PW)[(q * 4 + r) * PST + lr] = (u16)((__float_as_uint(p0_) + 0x8000u) >> 16);\
      (PW)[(q * 4 + r) * PST + 16 + lr] =                                          \
          (u16)((__float_as_uint(p1_) + 0x8000u) >> 16);                           \
    }                                                                              \
    if ((IT) > 0) {                                                                \
      v8bf pa_[4];                                                                 \
      _Pragma("unroll") for (int qs = 0; qs < 4; ++qs)                             \
          pa_[qs] = *reinterpret_cast<const v8bf*>(                                \
              (PR) + (qs * 16 + lr) * PST + q * 8);                                \
      __builtin_amdgcn_s_setprio(1);                                               \
      _Pragma("unroll") for (int cs = 0; cs < 4; ++cs)                             \
        _Pragma("unroll") for (int qs = 0; qs < 4; ++qs)                           \
          accO[qs * 4 + cs] = __builtin_amdgcn_mfma_f32_16x16x32_bf16(             \
              pa_[qs], VU[cs], accO[qs * 4 + cs], 0, 0, 0);                        \
      __builtin_amdgcn_s_setprio(0);                                               \
    }                                                                              \
    asm volatile("s_waitcnt vmcnt(4) lgkmcnt(0)\n\ts_barrier" ::: "memory");       \
  }

__global__ __launch_bounds__(256, 2) void k_flash(const u16* __restrict__ qT,
                                                  const u16* __restrict__ kT,
                                                  const u16* __restrict__ V,
                                                  u16* __restrict__ op0,
                                                  u16* __restrict__ op1,
                                                  float* __restrict__ ml,
                                                  const float* __restrict__ Mbuf,
                                                  int span) {
  __shared__ __align__(16) u16 ksh[2][32 * 256];   // 16 KB each, XOR-swizzled
  __shared__ __align__(16) u16 psh[2][64 * PST];   // double-buffered shared P
  int t = threadIdx.x;
  int w = t >> 6, lane = t & 63, lr = lane & 15, q = lane >> 4;
  // XCD-chunked bijective swizzle of the flat block id (total divisible by 8)
  int total = gridDim.x * gridDim.y * gridDim.z;
  int flat = blockIdx.x + gridDim.x * (blockIdx.y + gridDim.y * blockIdx.z);
  int nf = (flat & 7) * (total >> 3) + (flat >> 3);
  int h = (nf >> 6) & (gridDim.y - 1);             // js is a power of two
  int b = nf >> (6 + __builtin_ctz(gridDim.y));
  int i0 = (nf & 63) * 64;
  const u16* qb = qT + ((long)b * NN + i0 + w * 16) * C;
  const u16* kb = kT + (long)b * NN * C;
  const u16* vbw = V + (long)b * C * NN + (long)(w * 64) * NN;  // wave's channels
  // Cauchy-Schwarz upper bound on scores (log2 units); +1.5 slack: bf16 rounding
  // of stored q/k (norm partials are computed pre-rounding in k_qkv)
  float M = sqrtf(Mbuf[b] * Mbuf[4 + b]) + 1.5f;

  v8bf qf[8];
#pragma unroll
  for (int ks = 0; ks < 8; ++ks)
    qf[ks] = *reinterpret_cast<const v8bf*>(qb + lr * C + ks * 32 + q * 8);

  v4f accO[16];  // [qs*4+cs]: rows qs*16+q*4+r, channels w*64+cs*16+lr
#pragma unroll
  for (int ct = 0; ct < 16; ++ct)
#pragma unroll
    for (int r = 0; r < 4; ++r) accO[ct][r] = 0.f;
  float lsum[4] = {0.f, 0.f, 0.f, 0.f};

  u16* pw0 = psh[0] + w * 16 * PST;   // wave's 16 P rows, buffer 0
  u16* pw1 = psh[1] + w * 16 * PST;   // buffer 1
  const int xk = lr & 7;

  int jstart = h * span;
  int niter = span >> 5;               // always even (span = 2048)

  kissue(kb, ksh[0], jstart, w, lane);
  asm volatile("s_waitcnt vmcnt(0)\n\ts_barrier" ::: "memory");

  v8bf vA[4] = {}, vB[4] = {};
#pragma unroll 1
  for (int it2 = 0; it2 < niter; it2 += 2) {
    FLASH_STEP(it2,     vA, vB, pw0, psh[1], ksh[0], ksh[1])
    FLASH_STEP(it2 + 1, vB, vA, pw1, psh[0], ksh[1], ksh[0])
  }
  // final PV: tile niter-1 (odd): P in psh[1], V in vB
  {
    v8bf pa_[4];
#pragma unroll
    for (int qs = 0; qs < 4; ++qs)
      pa_[qs] = *reinterpret_cast<const v8bf*>(psh[1] + (qs * 16 + lr) * PST + q * 8);
#pragma unroll
    for (int cs = 0; cs < 4; ++cs)
#pragma unroll
      for (int qs = 0; qs < 4; ++qs)
        accO[qs * 4 + cs] = __builtin_amdgcn_mfma_f32_16x16x32_bf16(
            pa_[qs], vB[cs], accO[qs * 4 + cs], 0, 0, 0);
  }

  // one-time row-sum reduce across the 16 lanes sharing q (for ml only)
#pragma unroll
  for (int r = 0; r < 4; ++r) {
#pragma unroll
    for (int d = 1; d < 16; d <<= 1) lsum[r] += __shfl_xor(lsum[r], d, 64);
  }
  u16* opp = h == 0 ? op0 : op1;
  u16* ob = opp + ((long)b * NN + i0) * C;
#pragma unroll
  for (int qs = 0; qs < 4; ++qs)
#pragma unroll
    for (int cs = 0; cs < 4; ++cs)
#pragma unroll
      for (int r = 0; r < 4; ++r)
        ob[(qs * 16 + q * 4 + r) * C + w * 64 + cs * 16 + lr] =
            f2bf(accO[qs * 4 + cs][r]);
  if (lr == 0) {
    long rbase = ((long)h * CB + b) * NN + i0 + w * 16 + q * 4;
#pragma unroll
    for (int r = 0; r < 4; ++r) {
      ml[(rbase + r) * 2] = M;          // common bound => combine = (O0+O1)/(l0+l1)
      ml[(rbase + r) * 2 + 1] = lsum[r];
    }
  }
}

// ---------- fused combine + output projection + residual ----------
// out[b][gm][gn] = x[b][gm][gn] + bp[gm] + sum_c wp[gm][c] * O[gn][c]
// where O[gn][c] = (p0[gn][c] + p1[gn][c]) / (l0[gn] + l1[gn])  (common bound M).
__global__ __launch_bounds__(256) void k_gemmC(
    const u16* __restrict__ wpb, const u16* __restrict__ p0, const u16* __restrict__ p1,
    const float* __restrict__ ml, const float* __restrict__ bp,
    const float* __restrict__ x, float* __restrict__ out) {
  __shared__ __align__(16) u16 Ash[64 * 256];
  __shared__ __align__(16) u16 Bsh[64 * 256];
  int t = threadIdx.x;
  int w = t >> 6, lane = t & 63, lr = lane & 15, q = lane >> 4;
  int m0 = blockIdx.x * 64, n0 = blockIdx.y * 64, b = blockIdx.z;
  const int xk = lr & 7;
  const long nc = (long)NN * C;
  stage_dma(wpb + (long)m0 * 256, Ash, w, lane);
  // B-stage: combined O rows n0..n0+63, same XOR-swizzled layout as stage_dma
#pragma unroll
  for (int i = 0; i < 8; ++i) {
    int idx = w * 8 + i;
    int r = idx * 2 + (lane >> 5);
    int cg = (lane & 31) ^ (r & 7);
    long goff = (long)b * nc + (long)(n0 + r) * 256 + cg * 8;
    uint4 u0 = *reinterpret_cast<const uint4*>(p0 + goff);
    uint4 u1 = *reinterpret_cast<const uint4*>(p1 + goff);
    float l0 = ml[(((long)0 * CB + b) * NN + n0 + r) * 2 + 1];
    float l1 = ml[(((long)1 * CB + b) * NN + n0 + r) * 2 + 1];
    float inv = 1.0f / (l0 + l1);
    const u16* e0 = reinterpret_cast<const u16*>(&u0);
    const u16* e1 = reinterpret_cast<const u16*>(&u1);
    u16 cv[8];
#pragma unroll
    for (int k2 = 0; k2 < 8; ++k2)
      cv[k2] = f2bf((bf2f(e0[k2]) + bf2f(e1[k2])) * inv);
    *reinterpret_cast<uint4*>(Bsh + idx * 512 + lane * 8) =
        *reinterpret_cast<const uint4*>(cv);
  }
  asm volatile("s_waitcnt vmcnt(0) lgkmcnt(0)\n\ts_barrier" ::: "memory");
  v4f acc[4];
#pragma unroll
  for (int nt = 0; nt < 4; ++nt)
#pragma unroll
    for (int r = 0; r < 4; ++r) acc[nt][r] = 0.f;
#pragma unroll
  for (int ks = 0; ks < 8; ++ks) {
    int cg = ((ks * 4 + q) ^ xk) << 3;
    v8bf a = *reinterpret_cast<const v8bf*>(Ash + (w * 16 + lr) * 256 + cg);
#pragma unroll
    for (int nt = 0; nt < 4; ++nt) {
      v8bf bb = *reinterpret_cast<const v8bf*>(Bsh + (nt * 16 + lr) * 256 + cg);
      acc[nt] = __builtin_amdgcn_mfma_f32_16x16x32_bf16(a, bb, acc[nt], 0, 0, 0);
    }
  }
#pragma unroll
  for (int nt = 0; nt < 4; ++nt) {
#pragma unroll
    for (int r = 0; r < 4; ++r) {
      int gm = m0 + w * 16 + q * 4 + r;   // out channel
      int gn = n0 + nt * 16 + lr;         // voxel
      long addr = (long)b * nc + (long)gm * NN + gn;
      out[addr] = acc[nt][r] + bp[gm] + x[addr];
    }
  }
}

extern "C" void kernel_launch(void* const* d_in, const int* in_sizes, int n_in,
                              void* d_out, int out_size, void* d_ws, size_t ws_size,
                              hipStream_t stream) {
  const float* x = (const float*)d_in[0];
  const float* wq = (const float*)d_in[1];
  const float* bq = (const float*)d_in[2];
  const float* wk = (const float*)d_in[3];
  const float* bk = (const float*)d_in[4];
  const float* wv = (const float*)d_in[5];
  const float* bv = (const float*)d_in[6];
  const float* wp = (const float*)d_in[7];
  const float* bp = (const float*)d_in[8];
  float* out = (float*)d_out;
  char* ws = (char*)d_ws;

  const long SLOT = 8388608L;

  u16* wqb = (u16*)(ws + 0);
  u16* wkb = (u16*)(ws + 131072L);
  u16* wvb = (u16*)(ws + 262144L);
  u16* wpb = (u16*)(ws + 393216L);
  char* base = ws + 524288L;
  u16* op0 = (u16*)(base);                 // slot0
  u16* qTw = (u16*)(base + 1 * SLOT);      // slot1: q
  u16* kTw = (u16*)(base + 2 * SLOT);      // slot2: k
  u16* vw  = (u16*)(base + 3 * SLOT);      // slot3: v
  u16* op1 = (u16*)(base + 4 * SLOT);      // slot4 (head reused as Pn before k_flash)
  float* ml = (float*)(base + 5 * SLOT);   // 256 KB used (2 partials)
  float* Mbuf = ml + 131072;               // 8 floats
  float* Pn = (float*)op1;  // 512 KB norm partials; dead before k_flash writes op1

  k_prep<<<dim3(256, 4), 256, 0, stream>>>(wq, wk, wv, wp, wqb, wkb, wvb, wpb, Mbuf);
  k_qkv<<<dim3(64, 4, CB), 256, 0, stream>>>(x, wqb, wkb, wvb, bq, bk, bv, qTw, kTw,
                                             vw, Pn);
  k_norm<<<dim3(1, 2, CB), 256, 0, stream>>>(Pn, Mbuf);
  k_flash<<<dim3(64, 2, CB), 256, 0, stream>>>(qTw, kTw, vw, op0, op1, ml, Mbuf,
                                               NN / 2);
  k_gemmC<<<dim3(4, 64, CB), 256, 0, stream>>>(wpb, op0, op1, ml, bp, x, out);
}

// Round 15
// 227.916 us; speedup vs baseline: 1.0222x; 1.0222x over previous
//
#include <hip/hip_runtime.h>

typedef unsigned short u16;
typedef unsigned int u32;
typedef __bf16 v8bf __attribute__((ext_vector_type(8)));
typedef float v4f __attribute__((ext_vector_type(4)));

#define DEV __device__ __forceinline__

constexpr int CB = 4;     // batch
constexpr int C = 256;    // channels
constexpr int NN = 4096;  // voxels
constexpr float LOG2E = 1.4426950408889634f;
constexpr int PST = 44;   // P LDS row stride (u16): 88B = 22 banks -> conflict-free writes

DEV u16 f2bf(float f) {
  union { float f; u32 u; } v; v.f = f;
  u32 r = v.u + 0x7fffu + ((v.u >> 16) & 1u);  // RNE
  return (u16)(r >> 16);
}
DEV float bf2f(u16 h) {
  union { u32 u; float f; } v; v.u = ((u32)h) << 16; return v.f;
}

// async global->LDS DMA, 16B per lane; LDS dest = wave-uniform base + lane*16
DEV void dma16(const u16* g, const u16* lds_base) {
  __builtin_amdgcn_global_load_lds(
      (const __attribute__((address_space(1))) void*)(unsigned long long)g,
      (__attribute__((address_space(3))) void*)(u32)(unsigned long long)lds_base,
      16, 0, 0);
}

// ---------- transpose + bf16 convert + (fused) weight cvt + Mbuf zero ----------
// xT[b][n][c] = bf16(x[b][c][n]); first 1024 (z==0) blocks also convert one
// 256-element chunk of the 4 weight matrices (saves a separate cvt launch).
__global__ __launch_bounds__(256) void k_transpose(const float* __restrict__ x,
                                                   u16* __restrict__ xT,
                                                   const float* __restrict__ wq,
                                                   const float* __restrict__ wk,
                                                   const float* __restrict__ wv,
                                                   const float* __restrict__ wp,
                                                   u16* __restrict__ wqb,
                                                   u16* __restrict__ wkb,
                                                   u16* __restrict__ wvb,
                                                   u16* __restrict__ wpb,
                                                   float* __restrict__ Mbuf) {
  __shared__ float tile[32][33];
  int b = blockIdx.z;
  if (b == 0) {
    int flat = blockIdx.x + 128 * blockIdx.y;
    if (flat == 0 && threadIdx.x < 8) Mbuf[threadIdx.x] = 0.f;
    if (flat < 1024) {
      int wsel = flat >> 8;
      const float* s = wsel == 0 ? wq : wsel == 1 ? wk : wsel == 2 ? wv : wp;
      u16* d = wsel == 0 ? wqb : wsel == 1 ? wkb : wsel == 2 ? wvb : wpb;
      int i = (flat & 255) * 256 + threadIdx.x;
      d[i] = f2bf(s[i]);
    }
  }
  int n0 = blockIdx.x * 32, c0 = blockIdx.y * 32;
  int tx = threadIdx.x & 31, ty = threadIdx.x >> 5;  // 32 x 8
  const float* xb = x + (long)b * C * NN;
#pragma unroll
  for (int r = 0; r < 4; ++r)
    tile[ty + r * 8][tx] = xb[(long)(c0 + ty + r * 8) * NN + n0 + tx];
  __syncthreads();
  u16* xTb = xT + (long)b * NN * C;
#pragma unroll
  for (int r = 0; r < 4; ++r)
    xTb[(long)(n0 + ty + r * 8) * C + c0 + tx] = f2bf(tile[tx][ty + r * 8]);
}

// ---------- stage 64 rows x 256 u16 into linear LDS [64][256] via DMA ----------
// Column-group (8 u16) XOR-swizzle: LDS slot cg holds global cg ^ (row&7).
// Read side must apply the same XOR (T21: linear dest + pre-swizzled source).
DEV void stage_dma(const u16* __restrict__ g, const u16* lds, int w, int lane) {
#pragma unroll
  for (int i = 0; i < 8; ++i) {
    int idx = w * 8 + i;
    int r = idx * 2 + (lane >> 5);
    int cg = (lane & 31) ^ (r & 7);
    dma16(g + (long)r * 256 + cg * 8, lds + idx * 512);
  }
}

// ---------- fused q/k/v projection + row-norm^2 partials ----------
// Pn[tsel][quarter][b][gm]: per-64-ch-quarter sum of squares of the scaled q'
// (tsel=0) / k (tsel=1) row -- computed from the fp32 pre-rounding values in
// registers, so a separate 67MB re-read of q/k is eliminated.
__global__ __launch_bounds__(256) void k_qkv(
    const u16* __restrict__ xT, const u16* __restrict__ wqb, const u16* __restrict__ wkb,
    const u16* __restrict__ wvb, const float* __restrict__ bq, const float* __restrict__ bk,
    const float* __restrict__ bv, u16* __restrict__ qO, u16* __restrict__ kO,
    u16* __restrict__ vO, float* __restrict__ Pn) {
  __shared__ __align__(16) u16 Ash[64 * 256];
  __shared__ __align__(16) u16 Bsh[64 * 256];
  int t = threadIdx.x, w = t >> 6, lane = t & 63, lr = lane & 15, q = lane >> 4;
  int m0 = blockIdx.x * 64, n0 = blockIdx.y * 64, b = blockIdx.z;
  const int xk = lr & 7;
  stage_dma(xT + (long)b * NN * C + (long)m0 * 256, Ash, w, lane);
  stage_dma(wqb + (long)n0 * 256, Bsh, w, lane);
  asm volatile("s_waitcnt vmcnt(0)\n\ts_barrier" ::: "memory");
#pragma unroll 1
  for (int wsel = 0; wsel < 3; ++wsel) {
    v4f acc[4];
#pragma unroll
    for (int nt = 0; nt < 4; ++nt)
#pragma unroll
      for (int r = 0; r < 4; ++r) acc[nt][r] = 0.f;
#pragma unroll
    for (int ks = 0; ks < 8; ++ks) {
      int cg = ((ks * 4 + q) ^ xk) << 3;
      v8bf a = *reinterpret_cast<const v8bf*>(Ash + (w * 16 + lr) * 256 + cg);
#pragma unroll
      for (int nt = 0; nt < 4; ++nt) {
        v8bf bb = *reinterpret_cast<const v8bf*>(Bsh + (nt * 16 + lr) * 256 + cg);
        acc[nt] = __builtin_amdgcn_mfma_f32_16x16x32_bf16(a, bb, acc[nt], 0, 0, 0);
      }
    }
    // all waves done reading Ash/Bsh before we overwrite either
    asm volatile("s_waitcnt lgkmcnt(0)\n\ts_barrier" ::: "memory");
    if (wsel < 2) {
      stage_dma((wsel == 0 ? wkb : wvb) + (long)n0 * 256, Bsh, w, lane);
      // epilogue overlaps the B-restage DMA flight
      const float* bias = wsel == 0 ? bq : bk;
      float sn[4] = {0.f, 0.f, 0.f, 0.f};
#pragma unroll
      for (int nt = 0; nt < 4; ++nt) {
#pragma unroll
        for (int r = 0; r < 4; ++r) {
          int gm = m0 + w * 16 + q * 4 + r;   // voxel
          int gn = n0 + nt * 16 + lr;         // out channel
          float val = acc[nt][r] + bias[gn];
          if (wsel == 0) {
            float vs = val * (0.0625f * LOG2E);
            qO[((long)b * NN + gm) * C + gn] = f2bf(vs);
            sn[r] += vs * vs;
          } else {
            kO[((long)b * NN + gm) * C + gn] = f2bf(val);
            sn[r] += val * val;
          }
        }
      }
#pragma unroll
      for (int r = 0; r < 4; ++r) {
#pragma unroll
        for (int d = 1; d < 16; d <<= 1) sn[r] += __shfl_xor(sn[r], d, 64);
      }
      if (lr == 0) {
#pragma unroll
        for (int r = 0; r < 4; ++r)
          Pn[(((long)wsel * 4 + blockIdx.y) * CB + b) * NN + m0 + w * 16 + q * 4 + r] =
              sn[r];
      }
      asm volatile("s_waitcnt vmcnt(0)\n\ts_barrier" ::: "memory");
    } else {
      // V output: bounce through Ash (dead now) so the (C,N)-layout store
      // is coalesced uint4 instead of a 64-lane 2B scatter at 8KB stride.
      u16* Vt = Ash;  // 64 ch rows x stride 72 u16 (144B, debanked)
#pragma unroll
      for (int nt = 0; nt < 4; ++nt) {
#pragma unroll
        for (int r = 0; r < 4; ++r) {
          int gn_l = nt * 16 + lr;            // local out channel
          int gm_l = w * 16 + q * 4 + r;      // local voxel
          float val = acc[nt][r] + bv[n0 + gn_l];
          Vt[gn_l * 72 + gm_l] = f2bf(val);
        }
      }
      asm volatile("s_waitcnt lgkmcnt(0)\n\ts_barrier" ::: "memory");
      int row = t >> 2;                        // 0..63 local channel
      u16* vrow = vO + (long)b * C * NN + (long)(n0 + row) * NN + m0;
#pragma unroll
      for (int s2 = 0; s2 < 2; ++s2) {
        int seg = (t & 3) * 2 + s2;            // 0..7 (8 u16 each)
        *reinterpret_cast<uint4*>(vrow + seg * 8) =
            *reinterpret_cast<const uint4*>(Vt + row * 72 + seg * 8);
      }
    }
  }
}

// ---------- reduce the 4 ch-quarter partials -> per-batch max row-norm^2 ------
__global__ __launch_bounds__(256) void k_norm(const float* __restrict__ Pn,
                                              float* __restrict__ Mbuf) {
  int tsel = blockIdx.y, b = blockIdx.z;
  float mx = 0.f;
  for (int row = threadIdx.x; row < NN; row += 256) {
    float s = 0.f;
#pragma unroll
    for (int qr = 0; qr < 4; ++qr)
      s += Pn[(((long)tsel * 4 + qr) * CB + b) * NN + row];
    mx = fmaxf(mx, s);
  }
#pragma unroll
  for (int d = 1; d < 64; d <<= 1) mx = fmaxf(mx, __shfl_xor(mx, d, 64));
  if ((threadIdx.x & 63) == 0)
    atomicMax((u32*)(Mbuf + tsel * 4 + b), __float_as_uint(mx));
}

// issue the 4 K-DMAs for one 32-j tile (this wave's quarter), XOR-swizzled
DEV void kissue(const u16* kb, const u16* kshb, int j0, int w, int lane) {
#pragma unroll
  for (int i = 0; i < 4; ++i) {
    int idx = w * 4 + i;
    int kr = idx * 2 + (lane >> 5);
    int kc = (lane & 31) ^ (kr & 7);
    dma16(kb + (long)(j0 + kr) * 256 + kc * 8, kshb + idx * 512);
  }
}

// ---------- flash attention: single barrier per j-tile, software-pipelined ----
// qT,kT: (B,N,C) bf16 (q pre-scaled by C^-0.5*log2e); V: (B,C,N) bf16
// (frozen round-7 structure: 4 indep QK MFMA chains, setprio, XCD swizzle)
#define FLASH_STEP(IT, VL, VU, PW, PR, KC, KN)                                     \
  {                                                                                \
    int jn_ = ((IT) + 1 < niter) ? jstart + (((IT) + 1) << 5) : jstart;            \
    kissue(kb, (KN), jn_, w, lane);                                                \
    asm volatile("" ::: "memory"); /* keep K-DMAs older than V loads in vmcnt */   \
    {                                                                              \
      int jv_ = jstart + ((IT) << 5);                                              \
      _Pragma("unroll") for (int cs = 0; cs < 4; ++cs)                             \
          VL[cs] = *reinterpret_cast<const v8bf*>(                                 \
              vbw + (long)(cs * 16 + lr) * NN + jv_ + q * 8);                      \
    }                                                                              \
    v4f s0a_, s0b_, s1a_, s1b_;                                                    \
    _Pragma("unroll") for (int r = 0; r < 4; ++r) {                                \
      s0a_[r] = 0.f; s0b_[r] = 0.f; s1a_[r] = 0.f; s1b_[r] = 0.f;                  \
    }                                                                              \
    __builtin_amdgcn_s_setprio(1);                                                 \
    _Pragma("unroll") for (int ks = 0; ks < 4; ++ks) {                             \
      int cgA_ = ((ks * 4 + q) ^ xk) << 3;                                         \
      int cgB_ = (((ks + 4) * 4 + q) ^ xk) << 3;                                   \
      v8bf k0a_ = *reinterpret_cast<const v8bf*>((KC) + lr * 256 + cgA_);          \
      v8bf k1a_ = *reinterpret_cast<const v8bf*>((KC) + (16 + lr) * 256 + cgA_);   \
      v8bf k0b_ = *reinterpret_cast<const v8bf*>((KC) + lr * 256 + cgB_);          \
      v8bf k1b_ = *reinterpret_cast<const v8bf*>((KC) + (16 + lr) * 256 + cgB_);   \
      s0a_ = __builtin_amdgcn_mfma_f32_16x16x32_bf16(qf[ks], k0a_, s0a_, 0, 0, 0); \
      s1a_ = __builtin_amdgcn_mfma_f32_16x16x32_bf16(qf[ks], k1a_, s1a_, 0, 0, 0); \
      s0b_ = __builtin_amdgcn_mfma_f32_16x16x32_bf16(qf[ks + 4], k0b_, s0b_, 0, 0, 0); \
      s1b_ = __builtin_amdgcn_mfma_f32_16x16x32_bf16(qf[ks + 4], k1b_, s1b_, 0, 0, 0); \
    }                                                                              \
    __builtin_amdgcn_s_setprio(0);                                                 \
    v4f s0_ = s0a_ + s0b_;                                                         \
    v4f s1_ = s1a_ + s1b_;                                                         \
    _Pragma("unroll") for (int r = 0; r < 4; ++r) {                                \
      float p0_ = exp2f(s0_[r] - M);                                               \
      float p1_ = exp2f(s1_[r] - M);                                               \
      lsum[r] += p0_ + p1_;                                                        \
      (PW)[(q * 4 + r) * PST + lr] = (u16)((__float_as_uint(p0_) + 0x8000u) >> 16);\
      (PW)[(q * 4 + r) * PST + 16 + lr] =                                          \
          (u16)((__float_as_uint(p1_) + 0x8000u) >> 16);                           \
    }                                                                              \
    if ((IT) > 0) {                                                                \
      v8bf pa_[4];                                                                 \
      _Pragma("unroll") for (int qs = 0; qs < 4; ++qs)                             \
          pa_[qs] = *reinterpret_cast<const v8bf*>(                                \
              (PR) + (qs * 16 + lr) * PST + q * 8);                                \
      __builtin_amdgcn_s_setprio(1);                                               \
      _Pragma("unroll") for (int cs = 0; cs < 4; ++cs)                             \
        _Pragma("unroll") for (int qs = 0; qs < 4; ++qs)                           \
          accO[qs * 4 + cs] = __builtin_amdgcn_mfma_f32_16x16x32_bf16(             \
              pa_[qs], VU[cs], accO[qs * 4 + cs], 0, 0, 0);                        \
      __builtin_amdgcn_s_setprio(0);                                               \
    }                                                                              \
    asm volatile("s_waitcnt vmcnt(4) lgkmcnt(0)\n\ts_barrier" ::: "memory");       \
  }

__global__ __launch_bounds__(256, 2) void k_flash(const u16* __restrict__ qT,
                                                  const u16* __restrict__ kT,
                                                  const u16* __restrict__ V,
                                                  u16* __restrict__ op0,
                                                  u16* __restrict__ op1,
                                                  float* __restrict__ ml,
                                                  const float* __restrict__ Mbuf,
                                                  int span) {
  __shared__ __align__(16) u16 ksh[2][32 * 256];   // 16 KB each, XOR-swizzled
  __shared__ __align__(16) u16 psh[2][64 * PST];   // double-buffered shared P
  int t = threadIdx.x;
  int w = t >> 6, lane = t & 63, lr = lane & 15, q = lane >> 4;
  // XCD-chunked bijective swizzle of the flat block id (total divisible by 8)
  int total = gridDim.x * gridDim.y * gridDim.z;
  int flat = blockIdx.x + gridDim.x * (blockIdx.y + gridDim.y * blockIdx.z);
  int nf = (flat & 7) * (total >> 3) + (flat >> 3);
  int h = (nf >> 6) & (gridDim.y - 1);             // js is a power of two
  int b = nf >> (6 + __builtin_ctz(gridDim.y));
  int i0 = (nf & 63) * 64;
  const u16* qb = qT + ((long)b * NN + i0 + w * 16) * C;
  const u16* kb = kT + (long)b * NN * C;
  const u16* vbw = V + (long)b * C * NN + (long)(w * 64) * NN;  // wave's channels
  // Cauchy-Schwarz upper bound on scores (log2 units); +1.5 slack: bf16 rounding
  // of stored q/k (norm partials are computed pre-rounding in k_qkv)
  float M = sqrtf(Mbuf[b] * Mbuf[4 + b]) + 1.5f;

  v8bf qf[8];
#pragma unroll
  for (int ks = 0; ks < 8; ++ks)
    qf[ks] = *reinterpret_cast<const v8bf*>(qb + lr * C + ks * 32 + q * 8);

  v4f accO[16];  // [qs*4+cs]: rows qs*16+q*4+r, channels w*64+cs*16+lr
#pragma unroll
  for (int ct = 0; ct < 16; ++ct)
#pragma unroll
    for (int r = 0; r < 4; ++r) accO[ct][r] = 0.f;
  float lsum[4] = {0.f, 0.f, 0.f, 0.f};

  u16* pw0 = psh[0] + w * 16 * PST;   // wave's 16 P rows, buffer 0
  u16* pw1 = psh[1] + w * 16 * PST;   // buffer 1
  const int xk = lr & 7;

  int jstart = h * span;
  int niter = span >> 5;               // always even (span = 2048)

  kissue(kb, ksh[0], jstart, w, lane);
  asm volatile("s_waitcnt vmcnt(0)\n\ts_barrier" ::: "memory");

  v8bf vA[4] = {}, vB[4] = {};
#pragma unroll 1
  for (int it2 = 0; it2 < niter; it2 += 2) {
    FLASH_STEP(it2,     vA, vB, pw0, psh[1], ksh[0], ksh[1])
    FLASH_STEP(it2 + 1, vB, vA, pw1, psh[0], ksh[1], ksh[0])
  }
  // final PV: tile niter-1 (odd): P in psh[1], V in vB
  {
    v8bf pa_[4];
#pragma unroll
    for (int qs = 0; qs < 4; ++qs)
      pa_[qs] = *reinterpret_cast<const v8bf*>(psh[1] + (qs * 16 + lr) * PST + q * 8);
#pragma unroll
    for (int cs = 0; cs < 4; ++cs)
#pragma unroll
      for (int qs = 0; qs < 4; ++qs)
        accO[qs * 4 + cs] = __builtin_amdgcn_mfma_f32_16x16x32_bf16(
            pa_[qs], vB[cs], accO[qs * 4 + cs], 0, 0, 0);
  }

  // one-time row-sum reduce across the 16 lanes sharing q (for ml only)
#pragma unroll
  for (int r = 0; r < 4; ++r) {
#pragma unroll
    for (int d = 1; d < 16; d <<= 1) lsum[r] += __shfl_xor(lsum[r], d, 64);
  }
  u16* opp = h == 0 ? op0 : op1;
  u16* ob = opp + ((long)b * NN + i0) * C;
#pragma unroll
  for (int qs = 0; qs < 4; ++qs)
#pragma unroll
    for (int cs = 0; cs < 4; ++cs)
#pragma unroll
      for (int r = 0; r < 4; ++r)
        ob[(qs * 16 + q * 4 + r) * C + w * 64 + cs * 16 + lr] =
            f2bf(accO[qs * 4 + cs][r]);
  if (lr == 0) {
    long rbase = ((long)h * CB + b) * NN + i0 + w * 16 + q * 4;
#pragma unroll
    for (int r = 0; r < 4; ++r) {
      ml[(rbase + r) * 2] = M;          // common bound => combine = (O0+O1)/(l0+l1)
      ml[(rbase + r) * 2 + 1] = lsum[r];
    }
  }
}

// ---------- fused combine + output projection + residual ----------
// out[b][gm][gn] = x[b][gm][gn] + bp[gm] + sum_c wp[gm][c] * O[gn][c]
// where O[gn][c] = (p0[gn][c] + p1[gn][c]) / (l0[gn] + l1[gn])  (common bound M).
__global__ __launch_bounds__(256) void k_gemmC(
    const u16* __restrict__ wpb, const u16* __restrict__ p0, const u16* __restrict__ p1,
    const float* __restrict__ ml, const float* __restrict__ bp,
    const float* __restrict__ x, float* __restrict__ out) {
  __shared__ __align__(16) u16 Ash[64 * 256];
  __shared__ __align__(16) u16 Bsh[64 * 256];
  int t = threadIdx.x;
  int w = t >> 6, lane = t & 63, lr = lane & 15, q = lane >> 4;
  int m0 = blockIdx.x * 64, n0 = blockIdx.y * 64, b = blockIdx.z;
  const int xk = lr & 7;
  const long nc = (long)NN * C;
  stage_dma(wpb + (long)m0 * 256, Ash, w, lane);
  // B-stage: combined O rows n0..n0+63, same XOR-swizzled layout as stage_dma
#pragma unroll
  for (int i = 0; i < 8; ++i) {
    int idx = w * 8 + i;
    int r = idx * 2 + (lane >> 5);
    int cg = (lane & 31) ^ (r & 7);
    long goff = (long)b * nc + (long)(n0 + r) * 256 + cg * 8;
    uint4 u0 = *reinterpret_cast<const uint4*>(p0 + goff);
    uint4 u1 = *reinterpret_cast<const uint4*>(p1 + goff);
    float l0 = ml[(((long)0 * CB + b) * NN + n0 + r) * 2 + 1];
    float l1 = ml[(((long)1 * CB + b) * NN + n0 + r) * 2 + 1];
    float inv = 1.0f / (l0 + l1);
    const u16* e0 = reinterpret_cast<const u16*>(&u0);
    const u16* e1 = reinterpret_cast<const u16*>(&u1);
    u16 cv[8];
#pragma unroll
    for (int k2 = 0; k2 < 8; ++k2)
      cv[k2] = f2bf((bf2f(e0[k2]) + bf2f(e1[k2])) * inv);
    *reinterpret_cast<uint4*>(Bsh + idx * 512 + lane * 8) =
        *reinterpret_cast<const uint4*>(cv);
  }
  asm volatile("s_waitcnt vmcnt(0) lgkmcnt(0)\n\ts_barrier" ::: "memory");
  v4f acc[4];
#pragma unroll
  for (int nt = 0; nt < 4; ++nt)
#pragma unroll
    for (int r = 0; r < 4; ++r) acc[nt][r] = 0.f;
#pragma unroll
  for (int ks = 0; ks < 8; ++ks) {
    int cg = ((ks * 4 + q) ^ xk) << 3;
    v8bf a = *reinterpret_cast<const v8bf*>(Ash + (w * 16 + lr) * 256 + cg);
#pragma unroll
    for (int nt = 0; nt < 4; ++nt) {
      v8bf bb = *reinterpret_cast<const v8bf*>(Bsh + (nt * 16 + lr) * 256 + cg);
      acc[nt] = __builtin_amdgcn_mfma_f32_16x16x32_bf16(a, bb, acc[nt], 0, 0, 0);
    }
  }
#pragma unroll
  for (int nt = 0; nt < 4; ++nt) {
#pragma unroll
    for (int r = 0; r < 4; ++r) {
      int gm = m0 + w * 16 + q * 4 + r;   // out channel
      int gn = n0 + nt * 16 + lr;         // voxel
      long addr = (long)b * nc + (long)gm * NN + gn;
      out[addr] = acc[nt][r] + bp[gm] + x[addr];
    }
  }
}

extern "C" void kernel_launch(void* const* d_in, const int* in_sizes, int n_in,
                              void* d_out, int out_size, void* d_ws, size_t ws_size,
                              hipStream_t stream) {
  const float* x = (const float*)d_in[0];
  const float* wq = (const float*)d_in[1];
  const float* bq = (const float*)d_in[2];
  const float* wk = (const float*)d_in[3];
  const float* bk = (const float*)d_in[4];
  const float* wv = (const float*)d_in[5];
  const float* bv = (const float*)d_in[6];
  const float* wp = (const float*)d_in[7];
  const float* bp = (const float*)d_in[8];
  float* out = (float*)d_out;
  char* ws = (char*)d_ws;

  const long SLOT = 8388608L;

  u16* wqb = (u16*)(ws + 0);
  u16* wkb = (u16*)(ws + 131072L);
  u16* wvb = (u16*)(ws + 262144L);
  u16* wpb = (u16*)(ws + 393216L);
  char* base = ws + 524288L;
  u16* xT  = (u16*)(base);                 // slot0: xT, later op0
  u16* qTw = (u16*)(base + 1 * SLOT);      // slot1: q
  u16* kTw = (u16*)(base + 2 * SLOT);      // slot2: k
  u16* vw  = (u16*)(base + 3 * SLOT);      // slot3: v
  u16* op1 = (u16*)(base + 4 * SLOT);      // slot4 (head reused as Pn before k_flash)
  float* ml = (float*)(base + 5 * SLOT);   // 256 KB used (2 partials)
  float* Mbuf = ml + 131072;               // 8 floats
  u16* op0 = xT;            // xT dead after k_qkv
  float* Pn = (float*)op1;  // 512 KB norm partials; dead before k_flash writes op1

  k_transpose<<<dim3(128, 8, CB), 256, 0, stream>>>(x, xT, wq, wk, wv, wp, wqb, wkb,
                                                    wvb, wpb, Mbuf);
  k_qkv<<<dim3(64, 4, CB), 256, 0, stream>>>(xT, wqb, wkb, wvb, bq, bk, bv, qTw, kTw,
                                             vw, Pn);
  k_norm<<<dim3(1, 2, CB), 256, 0, stream>>>(Pn, Mbuf);
  k_flash<<<dim3(64, 2, CB), 256, 0, stream>>>(qTw, kTw, vw, op0, op1, ml, Mbuf,
                                               NN / 2);
  k_gemmC<<<dim3(4, 64, CB), 256, 0, stream>>>(wpb, op0, op1, ml, bp, x, out);
}